// Round 4
// baseline (238.150 us; speedup 1.0000x reference)
//
#include <hip/hip_runtime.h>

#define NN 8192
#define EE 65536

// ---------------------------------------------------------------------------
// k_pre: zero cnt[8192] + pack Wf1 = concat(nn1_w, nn1_b, root1) [640x48]
//        and Wf2 = concat(nn2_w, nn2_b, root2) [480x32] (source order already
//        matches the fused-K layout). 212*256 = 8192 + 30720 + 15360 threads.
// ---------------------------------------------------------------------------
__global__ __launch_bounds__(256) void k_pre(const float* __restrict__ w1,
                                             const float* __restrict__ b1,
                                             const float* __restrict__ r1,
                                             const float* __restrict__ w2,
                                             const float* __restrict__ b2,
                                             const float* __restrict__ r2,
                                             float* __restrict__ Wf1,
                                             float* __restrict__ Wf2,
                                             int* __restrict__ cnt) {
    int t = blockIdx.x * 256 + threadIdx.x;
    if (t < 8192) { cnt[t] = 0; return; }
    t -= 8192;
    if (t < 30720) {
        float v;
        if (t < 24576)      v = w1[t];
        else if (t < 27648) v = b1[t - 24576];
        else                v = r1[t - 27648];
        Wf1[t] = v;
        return;
    }
    t -= 30720;
    float v;
    if (t < 12288)      v = w2[t];
    else if (t < 13824) v = b2[t - 12288];
    else                v = r2[t - 13824];
    Wf2[t] = v;
}

__global__ __launch_bounds__(256) void k_hist(const int* __restrict__ ei,
                                              int* __restrict__ cnt) {
    int e = blockIdx.x * 256 + threadIdx.x;
    atomicAdd(&cnt[ei[EE + e]], 1);
}

// Single-block scan of 8192 degree counts -> row_ptr[8193] and cursor copy.
__global__ __launch_bounds__(1024) void k_scan(const int* __restrict__ cnt,
                                               int* __restrict__ row_ptr,
                                               int* __restrict__ cursor) {
    __shared__ int sd[1024];
    const int t = threadIdx.x;
    const int base = t * 8;
    int v[8];
    int s = 0;
#pragma unroll
    for (int j = 0; j < 8; j++) { v[j] = cnt[base + j]; s += v[j]; }
    sd[t] = s;
    __syncthreads();
    for (int off = 1; off < 1024; off <<= 1) {
        int a = sd[t];
        int b = (t >= off) ? sd[t - off] : 0;
        __syncthreads();
        sd[t] = a + b;
        __syncthreads();
    }
    int run = sd[t] - s;  // exclusive prefix
#pragma unroll
    for (int j = 0; j < 8; j++) {
        row_ptr[base + j] = run;
        cursor[base + j] = run;
        run += v[j];
    }
    if (t == 1023) row_ptr[8192] = run;
}

// cs2[slot] = (e, src): one 8B store; kills the ei[e] chain level in gathers.
__global__ __launch_bounds__(256) void k_scatter(const int* __restrict__ ei,
                                                 int* __restrict__ cursor,
                                                 int2* __restrict__ cs2) {
    int e = blockIdx.x * 256 + threadIdx.x;
    int s = ei[e];
    int d = ei[EE + e];
    int slot = atomicAdd(&cursor[d], 1);
    cs2[slot] = make_int2(e, s);
}

// ---------------------------------------------------------------------------
// k_y1: one wave per dst node, lane = input channel (64). Unrolled-by-4 edge
// loop: 4 independent x-row gathers in flight. Z1 row = [y0..y8 (576), x_d].
// ---------------------------------------------------------------------------
__global__ __launch_bounds__(256) void k_y1(const int2* __restrict__ cs2,
                                            const float* __restrict__ ea,
                                            const float* __restrict__ x,
                                            const int* __restrict__ row_ptr,
                                            float* __restrict__ Z1) {
    const int lane = threadIdx.x & 63;
    const int d = blockIdx.x * 4 + (threadIdx.x >> 6);
    float y[9];
#pragma unroll
    for (int f = 0; f < 9; f++) y[f] = 0.f;
    const int rp0 = row_ptr[d], rp1 = row_ptr[d + 1];
    int idx = rp0;
    for (; idx + 4 <= rp1; idx += 4) {
        int2 p0 = cs2[idx], p1 = cs2[idx + 1], p2 = cs2[idx + 2], p3 = cs2[idx + 3];
        float x0 = x[(size_t)p0.y * 64 + lane];
        float x1 = x[(size_t)p1.y * 64 + lane];
        float x2 = x[(size_t)p2.y * 64 + lane];
        float x3 = x[(size_t)p3.y * 64 + lane];
        float4 a00 = *(const float4*)(ea + (size_t)p0.x * 8);
        float4 a01 = *(const float4*)(ea + (size_t)p0.x * 8 + 4);
        float4 a10 = *(const float4*)(ea + (size_t)p1.x * 8);
        float4 a11 = *(const float4*)(ea + (size_t)p1.x * 8 + 4);
        float4 a20 = *(const float4*)(ea + (size_t)p2.x * 8);
        float4 a21 = *(const float4*)(ea + (size_t)p2.x * 8 + 4);
        float4 a30 = *(const float4*)(ea + (size_t)p3.x * 8);
        float4 a31 = *(const float4*)(ea + (size_t)p3.x * 8 + 4);
        y[0] += a00.x * x0 + a10.x * x1 + a20.x * x2 + a30.x * x3;
        y[1] += a00.y * x0 + a10.y * x1 + a20.y * x2 + a30.y * x3;
        y[2] += a00.z * x0 + a10.z * x1 + a20.z * x2 + a30.z * x3;
        y[3] += a00.w * x0 + a10.w * x1 + a20.w * x2 + a30.w * x3;
        y[4] += a01.x * x0 + a11.x * x1 + a21.x * x2 + a31.x * x3;
        y[5] += a01.y * x0 + a11.y * x1 + a21.y * x2 + a31.y * x3;
        y[6] += a01.z * x0 + a11.z * x1 + a21.z * x2 + a31.z * x3;
        y[7] += a01.w * x0 + a11.w * x1 + a21.w * x2 + a31.w * x3;
        y[8] += x0 + x1 + x2 + x3;
    }
    for (; idx < rp1; idx++) {
        int2 p = cs2[idx];
        float xv = x[(size_t)p.y * 64 + lane];
        float4 a0 = *(const float4*)(ea + (size_t)p.x * 8);
        float4 a1 = *(const float4*)(ea + (size_t)p.x * 8 + 4);
        y[0] += a0.x * xv; y[1] += a0.y * xv; y[2] += a0.z * xv; y[3] += a0.w * xv;
        y[4] += a1.x * xv; y[5] += a1.y * xv; y[6] += a1.z * xv; y[7] += a1.w * xv;
        y[8] += xv;
    }
    float* zr = Z1 + (size_t)d * 640;
#pragma unroll
    for (int f = 0; f < 9; f++) zr[f * 64 + lane] = y[f];
    zr[576 + lane] = x[(size_t)d * 64 + lane];
}

// ---------------------------------------------------------------------------
// k_g1: h1 = relu(Z1[8192x640] @ Wf1[640x48] + bias1).
// 128 blocks x 192 threads; block tile 64n x 48c; thread tile 4n x 4c;
// K-chunk 32. Per k per thread: 2x ds_read_b128 (24 cyc) vs 16 FMA (32 cyc)
// -> VALU-bound.
// ---------------------------------------------------------------------------
__global__ __launch_bounds__(192) void k_g1(const float* __restrict__ Z1,
                                            const float* __restrict__ Wf1,
                                            const float* __restrict__ bias1,
                                            float* __restrict__ h1) {
    __shared__ float Zs[32 * 64];   // [k][n]
    __shared__ float Ws[32 * 48];   // [k][c]
    const int t = threadIdx.x;
    const int nb = blockIdx.x * 64;
    const int n0 = (t & 15) * 4;
    const int c0 = (t >> 4) * 4;
    float acc[4][4];
#pragma unroll
    for (int i = 0; i < 4; i++)
#pragma unroll
        for (int j = 0; j < 4; j++) acc[i][j] = 0.f;
    for (int k0 = 0; k0 < 640; k0 += 32) {
        for (int idx = t; idx < 512; idx += 192) {
            int nn = idx >> 3, kk = (idx & 7) * 4;
            float4 v = *(const float4*)(Z1 + (size_t)(nb + nn) * 640 + k0 + kk);
            Zs[(kk + 0) * 64 + nn] = v.x;
            Zs[(kk + 1) * 64 + nn] = v.y;
            Zs[(kk + 2) * 64 + nn] = v.z;
            Zs[(kk + 3) * 64 + nn] = v.w;
        }
        for (int idx = t; idx < 384; idx += 192) {
            *(float4*)(Ws + idx * 4) = *(const float4*)(Wf1 + (size_t)k0 * 48 + idx * 4);
        }
        __syncthreads();
#pragma unroll 8
        for (int k = 0; k < 32; k++) {
            float4 a = *(const float4*)(Zs + k * 64 + n0);
            float4 w = *(const float4*)(Ws + k * 48 + c0);
            acc[0][0] += a.x * w.x; acc[0][1] += a.x * w.y; acc[0][2] += a.x * w.z; acc[0][3] += a.x * w.w;
            acc[1][0] += a.y * w.x; acc[1][1] += a.y * w.y; acc[1][2] += a.y * w.z; acc[1][3] += a.y * w.w;
            acc[2][0] += a.z * w.x; acc[2][1] += a.z * w.y; acc[2][2] += a.z * w.z; acc[2][3] += a.z * w.w;
            acc[3][0] += a.w * w.x; acc[3][1] += a.w * w.y; acc[3][2] += a.w * w.z; acc[3][3] += a.w * w.w;
        }
        __syncthreads();
    }
    float4 b = *(const float4*)(bias1 + c0);
#pragma unroll
    for (int i = 0; i < 4; i++) {
        float4 o;
        o.x = fmaxf(acc[i][0] + b.x, 0.f);
        o.y = fmaxf(acc[i][1] + b.y, 0.f);
        o.z = fmaxf(acc[i][2] + b.z, 0.f);
        o.w = fmaxf(acc[i][3] + b.w, 0.f);
        *(float4*)(h1 + (size_t)(nb + n0 + i) * 48 + c0) = o;
    }
}

// ---------------------------------------------------------------------------
// k_y2: one wave per dst, lanes 0..47 = h1 channel, unrolled-by-4.
// Z2 row = [y0..y8 (432), h1_d (48)].
// ---------------------------------------------------------------------------
__global__ __launch_bounds__(256) void k_y2(const int2* __restrict__ cs2,
                                            const float* __restrict__ ea,
                                            const float* __restrict__ h1,
                                            const int* __restrict__ row_ptr,
                                            float* __restrict__ Z2) {
    const int lane = threadIdx.x & 63;
    const int d = blockIdx.x * 4 + (threadIdx.x >> 6);
    if (lane >= 48) return;
    float y[9];
#pragma unroll
    for (int f = 0; f < 9; f++) y[f] = 0.f;
    const int rp0 = row_ptr[d], rp1 = row_ptr[d + 1];
    int idx = rp0;
    for (; idx + 4 <= rp1; idx += 4) {
        int2 p0 = cs2[idx], p1 = cs2[idx + 1], p2 = cs2[idx + 2], p3 = cs2[idx + 3];
        float x0 = h1[(size_t)p0.y * 48 + lane];
        float x1 = h1[(size_t)p1.y * 48 + lane];
        float x2 = h1[(size_t)p2.y * 48 + lane];
        float x3 = h1[(size_t)p3.y * 48 + lane];
        float4 a00 = *(const float4*)(ea + (size_t)p0.x * 8);
        float4 a01 = *(const float4*)(ea + (size_t)p0.x * 8 + 4);
        float4 a10 = *(const float4*)(ea + (size_t)p1.x * 8);
        float4 a11 = *(const float4*)(ea + (size_t)p1.x * 8 + 4);
        float4 a20 = *(const float4*)(ea + (size_t)p2.x * 8);
        float4 a21 = *(const float4*)(ea + (size_t)p2.x * 8 + 4);
        float4 a30 = *(const float4*)(ea + (size_t)p3.x * 8);
        float4 a31 = *(const float4*)(ea + (size_t)p3.x * 8 + 4);
        y[0] += a00.x * x0 + a10.x * x1 + a20.x * x2 + a30.x * x3;
        y[1] += a00.y * x0 + a10.y * x1 + a20.y * x2 + a30.y * x3;
        y[2] += a00.z * x0 + a10.z * x1 + a20.z * x2 + a30.z * x3;
        y[3] += a00.w * x0 + a10.w * x1 + a20.w * x2 + a30.w * x3;
        y[4] += a01.x * x0 + a11.x * x1 + a21.x * x2 + a31.x * x3;
        y[5] += a01.y * x0 + a11.y * x1 + a21.y * x2 + a31.y * x3;
        y[6] += a01.z * x0 + a11.z * x1 + a21.z * x2 + a31.z * x3;
        y[7] += a01.w * x0 + a11.w * x1 + a21.w * x2 + a31.w * x3;
        y[8] += x0 + x1 + x2 + x3;
    }
    for (; idx < rp1; idx++) {
        int2 p = cs2[idx];
        float xv = h1[(size_t)p.y * 48 + lane];
        float4 a0 = *(const float4*)(ea + (size_t)p.x * 8);
        float4 a1 = *(const float4*)(ea + (size_t)p.x * 8 + 4);
        y[0] += a0.x * xv; y[1] += a0.y * xv; y[2] += a0.z * xv; y[3] += a0.w * xv;
        y[4] += a1.x * xv; y[5] += a1.y * xv; y[6] += a1.z * xv; y[7] += a1.w * xv;
        y[8] += xv;
    }
    float* zr = Z2 + (size_t)d * 480;
#pragma unroll
    for (int f = 0; f < 9; f++) zr[f * 48 + lane] = y[f];
    zr[432 + lane] = h1[(size_t)d * 48 + lane];
}

// ---------------------------------------------------------------------------
// k_g2: h2 = relu(Z2[8192x480] @ Wf2[480x32] + b2); heads fused:
// hcat[d] = [h2@mu_w, h2@ls_w] * dinv[d]  (pre-scaled for the GCN gather);
// out init = self-loop term + bias. 128 blocks x 128 threads, tile 64n x 32c,
// thread 4n x 4c, K-chunk 32.
// ---------------------------------------------------------------------------
__global__ __launch_bounds__(128) void k_g2(const float* __restrict__ Z2,
                                            const float* __restrict__ Wf2,
                                            const float* __restrict__ bias2,
                                            const float* __restrict__ mu_w,
                                            const float* __restrict__ mu_b,
                                            const float* __restrict__ ls_w,
                                            const float* __restrict__ ls_b,
                                            const int* __restrict__ row_ptr,
                                            float* __restrict__ hcat,
                                            float* __restrict__ dinv,
                                            float* __restrict__ out) {
    __shared__ float Zs[32 * 64];    // [k][n]
    __shared__ float Ws[32 * 32];    // [k][c]
    __shared__ float Whs[2 * 32 * 16];  // mu_w then ls_w
    __shared__ float h2s[64 * 33];
    const int t = threadIdx.x;
    const int nb = blockIdx.x * 64;
    const int n0 = (t & 15) * 4;
    const int c0 = (t >> 4) * 4;
    // stage head weights
    for (int idx = t; idx < 128; idx += 128) {
        *(float4*)(Whs + idx * 4) =
            (idx < 128) ? ((idx < 128 && idx * 4 < 512)
                               ? *(const float4*)(mu_w + idx * 4)
                               : make_float4(0, 0, 0, 0))
                        : make_float4(0, 0, 0, 0);
    }
    for (int idx = t; idx < 128; idx += 128) {
        *(float4*)(Whs + 512 + idx * 4) = *(const float4*)(ls_w + idx * 4);
    }
    float acc[4][4];
#pragma unroll
    for (int i = 0; i < 4; i++)
#pragma unroll
        for (int j = 0; j < 4; j++) acc[i][j] = 0.f;
    for (int k0 = 0; k0 < 480; k0 += 32) {
        for (int idx = t; idx < 512; idx += 128) {
            int nn = idx >> 3, kk = (idx & 7) * 4;
            float4 v = *(const float4*)(Z2 + (size_t)(nb + nn) * 480 + k0 + kk);
            Zs[(kk + 0) * 64 + nn] = v.x;
            Zs[(kk + 1) * 64 + nn] = v.y;
            Zs[(kk + 2) * 64 + nn] = v.z;
            Zs[(kk + 3) * 64 + nn] = v.w;
        }
        for (int idx = t; idx < 256; idx += 128) {
            *(float4*)(Ws + idx * 4) = *(const float4*)(Wf2 + (size_t)k0 * 32 + idx * 4);
        }
        __syncthreads();
#pragma unroll 8
        for (int k = 0; k < 32; k++) {
            float4 a = *(const float4*)(Zs + k * 64 + n0);
            float4 w = *(const float4*)(Ws + k * 32 + c0);
            acc[0][0] += a.x * w.x; acc[0][1] += a.x * w.y; acc[0][2] += a.x * w.z; acc[0][3] += a.x * w.w;
            acc[1][0] += a.y * w.x; acc[1][1] += a.y * w.y; acc[1][2] += a.y * w.z; acc[1][3] += a.y * w.w;
            acc[2][0] += a.z * w.x; acc[2][1] += a.z * w.y; acc[2][2] += a.z * w.z; acc[2][3] += a.z * w.w;
            acc[3][0] += a.w * w.x; acc[3][1] += a.w * w.y; acc[3][2] += a.w * w.z; acc[3][3] += a.w * w.w;
        }
        __syncthreads();
    }
    float4 b2v = *(const float4*)(bias2 + c0);
#pragma unroll
    for (int i = 0; i < 4; i++) {
        h2s[(n0 + i) * 33 + c0 + 0] = fmaxf(acc[i][0] + b2v.x, 0.f);
        h2s[(n0 + i) * 33 + c0 + 1] = fmaxf(acc[i][1] + b2v.y, 0.f);
        h2s[(n0 + i) * 33 + c0 + 2] = fmaxf(acc[i][2] + b2v.z, 0.f);
        h2s[(n0 + i) * 33 + c0 + 3] = fmaxf(acc[i][3] + b2v.w, 0.f);
    }
    __syncthreads();
    // heads: thread -> (node n = t>>1, head q = t&1), 16 outputs
    const int n = t >> 1;
    const int q = t & 1;
    const float* wh = Whs + q * 512;
    const float* bh = q ? ls_b : mu_b;
    float a16[16];
#pragma unroll
    for (int j = 0; j < 16; j++) a16[j] = 0.f;
#pragma unroll 8
    for (int i = 0; i < 32; i++) {
        float v = h2s[n * 33 + i];
#pragma unroll
        for (int j = 0; j < 16; j++) a16[j] += v * wh[i * 16 + j];
    }
    const int d = nb + n;
    const int degi = row_ptr[d + 1] - row_ptr[d] + 1;
    const float invd = 1.f / (float)degi;
    const float di = rsqrtf((float)degi);
    if (t < 64 && q == 0) dinv[nb + (t >> 1)] = 0.f;  // placeholder avoid unused warn
    if (q == 0) dinv[d] = di;
    float* hc = hcat + (size_t)d * 32 + q * 16;
    float* op = out + (q ? (size_t)NN * 16 : (size_t)0) + (size_t)d * 16;
#pragma unroll
    for (int j = 0; j < 16; j += 4) {
        float4 hv, ov;
        hv.x = a16[j] * di;     ov.x = a16[j] * invd + bh[j];
        hv.y = a16[j + 1] * di; ov.y = a16[j + 1] * invd + bh[j + 1];
        hv.z = a16[j + 2] * di; ov.z = a16[j + 2] * invd + bh[j + 2];
        hv.w = a16[j + 3] * di; ov.w = a16[j + 3] * invd + bh[j + 3];
        *(float4*)(hc + j) = hv;
        *(float4*)(op + j) = ov;
    }
}

// ---------------------------------------------------------------------------
// k_gcn: half-wave (32 lanes) per dst: out[d] += dinv[d] * sum_s hcat[s]
// (hcat pre-scaled by dinv[s]). Unrolled by 4.
// ---------------------------------------------------------------------------
__global__ __launch_bounds__(256) void k_gcn(const int2* __restrict__ cs2,
                                             const int* __restrict__ row_ptr,
                                             const float* __restrict__ hcat,
                                             const float* __restrict__ dinv,
                                             float* __restrict__ out) {
    const int t = threadIdx.x;
    const int lane32 = t & 31;
    const int d = blockIdx.x * 8 + (t >> 5);
    float acc = 0.f;
    const int rp0 = row_ptr[d], rp1 = row_ptr[d + 1];
    int idx = rp0;
    for (; idx + 4 <= rp1; idx += 4) {
        int2 p0 = cs2[idx], p1 = cs2[idx + 1], p2 = cs2[idx + 2], p3 = cs2[idx + 3];
        float v0 = hcat[(size_t)p0.y * 32 + lane32];
        float v1 = hcat[(size_t)p1.y * 32 + lane32];
        float v2 = hcat[(size_t)p2.y * 32 + lane32];
        float v3 = hcat[(size_t)p3.y * 32 + lane32];
        acc += (v0 + v1) + (v2 + v3);
    }
    for (; idx < rp1; idx++) {
        int2 p = cs2[idx];
        acc += hcat[(size_t)p.y * 32 + lane32];
    }
    acc *= dinv[d];
    const int col = lane32 & 15;
    const size_t addr = (lane32 < 16) ? ((size_t)d * 16 + col)
                                      : ((size_t)NN * 16 + (size_t)d * 16 + col);
    out[addr] += acc;
}

extern "C" void kernel_launch(void* const* d_in, const int* in_sizes, int n_in,
                              void* d_out, int out_size, void* d_ws, size_t ws_size,
                              hipStream_t stream) {
    const int*   ei    = (const int*)d_in[1];
    const float* x     = (const float*)d_in[0];
    const float* ea    = (const float*)d_in[2];
    const float* nn1_w = (const float*)d_in[3];
    const float* nn1_b = (const float*)d_in[4];
    const float* root1 = (const float*)d_in[5];
    const float* bias1 = (const float*)d_in[6];
    const float* nn2_w = (const float*)d_in[7];
    const float* nn2_b = (const float*)d_in[8];
    const float* root2 = (const float*)d_in[9];
    const float* bias2 = (const float*)d_in[10];
    const float* mu_w  = (const float*)d_in[11];
    const float* mu_b  = (const float*)d_in[12];
    const float* ls_w  = (const float*)d_in[13];
    const float* ls_b  = (const float*)d_in[14];
    float* out = (float*)d_out;

    // Workspace layout (float units; every segment start divisible by 4)
    float* W       = (float*)d_ws;
    float* Wf1     = W;                        //    30,720
    float* Wf2     = Wf1 + 30720;              //    15,360
    int*   cnt     = (int*)(Wf2 + 15360);      //     8,192
    int*   row_ptr = cnt + 8192;               //     8,196
    int*   cursor  = row_ptr + 8196;           //     8,192
    int2*  cs2     = (int2*)(cursor + 8192);   //    65,536 int2 = 131,072
    float* Z1      = (float*)(cs2 + 65536);    // 5,242,880
    float* Z2      = Z1 + 5242880;             // 3,932,160
    float* h1      = Z2 + 3932160;             //   393,216
    float* hcat    = h1 + 393216;              //   262,144
    float* dinv    = hcat + 262144;            //     8,192
    // total ~40 MB

    k_pre<<<dim3(212), dim3(256), 0, stream>>>(nn1_w, nn1_b, root1,
                                               nn2_w, nn2_b, root2,
                                               Wf1, Wf2, cnt);
    k_hist<<<dim3(256), dim3(256), 0, stream>>>(ei, cnt);
    k_scan<<<dim3(1), dim3(1024), 0, stream>>>(cnt, row_ptr, cursor);
    k_scatter<<<dim3(256), dim3(256), 0, stream>>>(ei, cursor, cs2);
    k_y1<<<dim3(2048), dim3(256), 0, stream>>>(cs2, ea, x, row_ptr, Z1);
    k_g1<<<dim3(128), dim3(192), 0, stream>>>(Z1, Wf1, bias1, h1);
    k_y2<<<dim3(2048), dim3(256), 0, stream>>>(cs2, ea, h1, row_ptr, Z2);
    k_g2<<<dim3(128), dim3(128), 0, stream>>>(Z2, Wf2, bias2, mu_w, mu_b,
                                              ls_w, ls_b, row_ptr, hcat, dinv, out);
    k_gcn<<<dim3(1024), dim3(256), 0, stream>>>(cs2, row_ptr, hcat, dinv, out);
}